// Round 18
// baseline (355.860 us; speedup 1.0000x reference)
//
#include <hip/hip_runtime.h>
#include <hip/hip_bf16.h>

typedef short bf16x8 __attribute__((ext_vector_type(8)));
typedef float f32x4 __attribute__((ext_vector_type(4)));
typedef float f32x16 __attribute__((ext_vector_type(16)));
typedef unsigned short ushort8v __attribute__((ext_vector_type(8)));

#define SBAR() asm volatile("s_barrier" ::: "memory")

__device__ __forceinline__ unsigned short f2bf(float f) {
  unsigned u = __builtin_bit_cast(unsigned, f);
  u += 0x7fffu + ((u >> 16) & 1u);   // round-to-nearest-even
  return (unsigned short)(u >> 16);
}

__device__ __forceinline__ void gload_lds16(const unsigned short* g, unsigned short* l) {
  __builtin_amdgcn_global_load_lds((const __attribute__((address_space(1))) void*)g,
                                   (__attribute__((address_space(3))) void*)l, 16, 0, 0);
}

// ---------------- fused prep: xb = bf16(x); wb = bf16(W + scale*B@A) ----------------
__global__ __launch_bounds__(256) void prep_kernel(const float* __restrict__ x,
                                                   const float* __restrict__ W,
                                                   const float* __restrict__ A,
                                                   const float* __restrict__ Bm,
                                                   unsigned short* __restrict__ xb,
                                                   unsigned short* __restrict__ wb,
                                                   float scale, int K, int R, int n8, int t8) {
  int i = blockIdx.x * 256 + threadIdx.x;
  if (i < n8) {
    const float4* p = (const float4*)x + (size_t)i * 2;
    float4 a = p[0], b = p[1];
    ushort8v v;
    v[0] = f2bf(a.x); v[1] = f2bf(a.y); v[2] = f2bf(a.z); v[3] = f2bf(a.w);
    v[4] = f2bf(b.x); v[5] = f2bf(b.y); v[6] = f2bf(b.z); v[7] = f2bf(b.w);
    *((ushort8v*)xb + i) = v;
    return;
  }
  int idx = i - n8;
  if (idx >= t8) return;
  int perRow = K >> 3;
  int n = idx / perRow;
  int d0 = (idx - n * perRow) << 3;
  const float4* wp = (const float4*)(W + (size_t)n * K + d0);
  float4 w0 = wp[0], w1 = wp[1];
  float acc[8] = {w0.x, w0.y, w0.z, w0.w, w1.x, w1.y, w1.z, w1.w};
#pragma unroll 4
  for (int r = 0; r < R; ++r) {
    float c = Bm[(size_t)n * R + r] * scale;
    const float4* ap = (const float4*)(A + (size_t)r * K + d0);
    float4 a0 = ap[0], a1 = ap[1];
    acc[0] += c * a0.x; acc[1] += c * a0.y; acc[2] += c * a0.z; acc[3] += c * a0.w;
    acc[4] += c * a1.x; acc[5] += c * a1.y; acc[6] += c * a1.z; acc[7] += c * a1.w;
  }
  ushort8v v;
#pragma unroll
  for (int j = 0; j < 8; ++j) v[j] = f2bf(acc[j]);
  *((ushort8v*)wb + idx) = v;
}

// -------- 256x256 bf16 GEMM: r11 quarter-phase schedule + 32x32x16 MFMA --------
// Identical to r11 (staging map, swizzle, vmcnt(6)@P4/P8 ledger, barriers,
// per-phase read counts 12/4/4/4) but fragments use v_mfma_f32_32x32x16_bf16
// (2382 TF ubench vs 2075 for 16x16x32: -17% MFMA issue cycles, same FLOPs).
// Per phase: 8 MFMA (2 n-subtiles x 4 k-slices). acc = 8 x f32x16 = 128 regs.
// A frag: lane reads A[row=(l&31)][k=ks*16+(l>>5)*8..+7]; C/D: col=lane&31,
// row=(reg&3)+8*(reg>>2)+4*(lane>>5) (HW-verified m74/m101).
// A quarter-major sites, B 64-row sites, chunk-XOR swizzle (measured 0 confl).
__global__ __launch_bounds__(512, 2) void gemm256_bt_bias(const unsigned short* __restrict__ Xb,
                                                          const unsigned short* __restrict__ Wb,
                                                          const float* __restrict__ bias,
                                                          float* __restrict__ C,
                                                          int M, int N, int K) {
  __shared__ __align__(16) char lds[131072];
  const int t = threadIdx.x;
  const int wave = t >> 6, lane = t & 63;
  const int l31 = lane & 31, hl = lane >> 5;
  const int wr = (wave >> 2), wc = wave & 3;

  const int NTn = N >> 8;
  const int nwg = gridDim.x;
  int bid = blockIdx.x;
  if ((nwg & 7) == 0) bid = (bid & 7) * (nwg >> 3) + (bid >> 3);  // XCD swizzle
  const int tm = bid / NTn, tn = bid % NTn;
  const int m0 = tm << 8, n0 = tn << 8;

  // ---- staging sources (pre-swizzled global chunk; r11 verbatim) ----
  const int lr = t >> 3;                                  // row-in-site 0..63
  const int gch8 = ((t & 7) ^ (lr & 7)) << 3;             // swizzled chunk, elems
  const unsigned short* pa0 = Xb + (size_t)(m0 + ((lr >> 5) << 7) + (lr & 31)) * K + gch8;
  const unsigned short* pb0 = Wb + (size_t)(n0 + lr) * K + gch8;
  const size_t K32 = (size_t)32 * K, K64v = (size_t)64 * K;
  const int sdst = t * 16;

  // ---- per-lane read byte-offsets for 32x32x16 fragments ----
  // A site q: [q*8192 + wr*4096 + r32*128 + swz*16]; chunk = ks*2 + hl.
  int oA[4], oB[8];
#pragma unroll
  for (int ks = 0; ks < 4; ++ks)
    oA[ks] = wr * 4096 + l31 * 128 + (((ks * 2 + hl) ^ (l31 & 7)) << 4);
#pragma unroll
  for (int n = 0; n < 2; ++n)
#pragma unroll
    for (int ks = 0; ks < 4; ++ks)
      oB[n * 4 + ks] = 32768 + wc * 8192 + n * 4096 + l31 * 128 +
                       (((ks * 2 + hl) ^ (l31 & 7)) << 4);

  f32x16 acc[8];
#pragma unroll
  for (int i = 0; i < 8; ++i) acc[i] = (f32x16)(0.f);

  bf16x8 aQ[4], bQ[8];

#define STGA(BUF, q, COL) gload_lds16(pa0 + (size_t)(q) * K32 + (COL), \
    (unsigned short*)((char*)lds + (BUF) * 65536 + (q) * 8192 + sdst))
#define STGB(BUF, s, COL) gload_lds16(pb0 + (size_t)(s) * K64v + (COL), \
    (unsigned short*)((char*)lds + (BUF) * 65536 + 32768 + (s) * 8192 + sdst))

#define RDB32(BUF) do { \
    _Pragma("unroll") for (int i = 0; i < 8; ++i) \
      bQ[i] = *(const bf16x8*)((char*)lds + (BUF) * 65536 + oB[i]); } while (0)
#define RDA32(BUF, q) do { \
    _Pragma("unroll") for (int ks = 0; ks < 4; ++ks) \
      aQ[ks] = *(const bf16x8*)((char*)lds + (BUF) * 65536 + (q) * 8192 + oA[ks]); } while (0)

#define MMQ(q) do { __builtin_amdgcn_s_setprio(1); \
    _Pragma("unroll") for (int n = 0; n < 2; ++n) \
    _Pragma("unroll") for (int ks = 0; ks < 4; ++ks) \
      acc[(q)*2+n] = __builtin_amdgcn_mfma_f32_32x32x16_bf16( \
          aQ[ks], bQ[n*4+ks], acc[(q)*2+n], 0, 0, 0); \
    __builtin_amdgcn_s_setprio(0); } while (0)

  // phase: reads -> stage -> [vmcnt] -> SBAR -> lgkm(0) -> 8 MFMA -> SBAR
#define PH(BUF, q, STGS, WAITS) do { \
    RDA32(BUF, q); \
    STGS WAITS \
    SBAR(); \
    asm volatile("s_waitcnt lgkmcnt(0)" ::: "memory"); \
    __builtin_amdgcn_sched_barrier(0); \
    MMQ(q); \
    SBAR(); } while (0)
#define PH_B(BUF, STGS, WAITS) do { \
    RDB32(BUF); RDA32(BUF, 0); \
    STGS WAITS \
    SBAR(); \
    asm volatile("s_waitcnt lgkmcnt(0)" ::: "memory"); \
    __builtin_amdgcn_sched_barrier(0); \
    MMQ(0); \
    SBAR(); } while (0)

  // iter = 2 K-tiles (buf0 then buf1). Stage ledger (r11 verbatim, proven):
  // P1: Aq2,Aq3(c+1)  P2: Bs0,Bs1(c+2)  P3: Bs2,Bs3(c+2)  P4: Aq0,Aq1(c+2)
  // P5: Aq2,Aq3(c+2)  P6: Bs0,Bs1(c+3)  P7: Bs2,Bs3(c+3)  P8: Aq0,Aq1(c+3)
  // vmcnt(6)@P4 and @P8 certify everything older than the newest 6 loads.
#define ITER(DOSTG, VM4, VM8) do { \
    PH_B(0, { STGA(1, 2, col + 64); STGA(1, 3, col + 64); }, ;); \
    PH(0, 1, { if (DOSTG) { STGB(0, 0, col + 128); STGB(0, 1, col + 128); } }, ;); \
    PH(0, 2, { if (DOSTG) { STGB(0, 2, col + 128); STGB(0, 3, col + 128); } }, ;); \
    PH(0, 3, { if (DOSTG) { STGA(0, 0, col + 128); STGA(0, 1, col + 128); } }, \
       asm volatile("s_waitcnt vmcnt(" VM4 ")" ::: "memory");); \
    PH_B(1, { if (DOSTG) { STGA(0, 2, col + 128); STGA(0, 3, col + 128); } }, ;); \
    PH(1, 1, { if (DOSTG) { STGB(1, 0, col + 192); STGB(1, 1, col + 192); } }, ;); \
    PH(1, 2, { if (DOSTG) { STGB(1, 2, col + 192); STGB(1, 3, col + 192); } }, ;); \
    PH(1, 3, { if (DOSTG) { STGA(1, 0, col + 192); STGA(1, 1, col + 192); } }, \
       asm volatile("s_waitcnt vmcnt(" VM8 ")" ::: "memory");); \
    col += 128; } while (0)

  // prologue: tile0 full (8), B(1) (4), Aq0,Aq1(1) (2) = 14 loads;
  // vmcnt(6) certifies tile0, leaves exactly the steady-state 6 in flight.
  size_t col = 0;
  STGB(0, 0, 0); STGB(0, 1, 0); STGB(0, 2, 0); STGB(0, 3, 0);
  STGA(0, 0, 0); STGA(0, 1, 0); STGA(0, 2, 0); STGA(0, 3, 0);
  STGB(1, 0, 64); STGB(1, 1, 64); STGB(1, 2, 64); STGB(1, 3, 64);
  STGA(1, 0, 64); STGA(1, 1, 64);
  asm volatile("s_waitcnt vmcnt(6)" ::: "memory");
  SBAR();

  const int NITER = K >> 7;   // launcher guarantees K%128==0, K>=256
  for (int it = 0; it < NITER - 1; ++it) ITER(1, "6", "6");
  ITER(0, "0", "0");          // last iter: P1 still stages Aq2,Aq3(NT-1); drain

  // epilogue: 32x32 D map col = lane&31, row = (reg&3)+8*(reg>>2)+4*(lane>>5)
#pragma unroll
  for (int q = 0; q < 4; ++q)
#pragma unroll
    for (int n = 0; n < 2; ++n) {
      int colI = n0 + wc * 64 + n * 32 + l31;
      float bv = bias[colI];
#pragma unroll
      for (int g = 0; g < 4; ++g) {
        int row = m0 + wr * 128 + q * 32 + g * 8 + hl * 4;
        float* cp = C + (size_t)row * N + colI;
#pragma unroll
        for (int r = 0; r < 4; ++r) cp[(size_t)r * N] = acc[q * 2 + n][g * 4 + r] + bv;
      }
    }
#undef STGA
#undef STGB
#undef RDB32
#undef RDA32
#undef MMQ
#undef PH
#undef PH_B
#undef ITER
}

// ---------------- 128x128 m97-structure fallback GEMM ----------------
__global__ __launch_bounds__(256) void gemm_bt_bias(const unsigned short* __restrict__ Xb,
                                                    const unsigned short* __restrict__ Wb,
                                                    const float* __restrict__ bias,
                                                    float* __restrict__ C,
                                                    int M, int N, int K) {
  __shared__ unsigned short sA[128 * 32];
  __shared__ unsigned short sB[128 * 32];
  const int t = threadIdx.x;
  const int wave = t >> 6, lane = t & 63;
  const int NT = N >> 7;
  const int nwg = gridDim.x;
  int bid = blockIdx.x;
  if ((nwg & 7) == 0) bid = (bid & 7) * (nwg >> 3) + (bid >> 3);
  const int tm = bid / NT, tn = bid % NT;
  const int m0 = tm << 7, n0 = tn << 7;
  const int wr = wave >> 1, wc = wave & 1;

  f32x4 acc[4][4];
#pragma unroll
  for (int m = 0; m < 4; ++m)
#pragma unroll
    for (int n = 0; n < 4; ++n) acc[m][n] = (f32x4){0.f, 0.f, 0.f, 0.f};

  const unsigned short* gA0 = Xb + (size_t)(m0 + (t >> 2)) * K + (t & 3) * 8;
  const unsigned short* gA1 = Xb + (size_t)(m0 + 64 + (t >> 2)) * K + (t & 3) * 8;
  const unsigned short* gB0 = Wb + (size_t)(n0 + (t >> 2)) * K + (t & 3) * 8;
  const unsigned short* gB1 = Wb + (size_t)(n0 + 64 + (t >> 2)) * K + (t & 3) * 8;
  unsigned short* lA0 = sA + (size_t)(wave * 64) * 8;
  unsigned short* lA1 = sA + (size_t)(256 + wave * 64) * 8;
  unsigned short* lB0 = sB + (size_t)(wave * 64) * 8;
  unsigned short* lB1 = sB + (size_t)(256 + wave * 64) * 8;

  const int rrow = lane & 15;
  const int rk = (lane >> 4) * 8;

  for (int k0 = 0; k0 < K; k0 += 32) {
    gload_lds16(gA0 + k0, lA0);
    gload_lds16(gA1 + k0, lA1);
    gload_lds16(gB0 + k0, lB0);
    gload_lds16(gB1 + k0, lB1);
    __syncthreads();
    bf16x8 af[4], bfr[4];
#pragma unroll
    for (int m = 0; m < 4; ++m)
      af[m] = *(const bf16x8*)&sA[(size_t)(wr * 64 + m * 16 + rrow) * 32 + rk];
#pragma unroll
    for (int n = 0; n < 4; ++n)
      bfr[n] = *(const bf16x8*)&sB[(size_t)(wc * 64 + n * 16 + rrow) * 32 + rk];
#pragma unroll
    for (int m = 0; m < 4; ++m)
#pragma unroll
      for (int n = 0; n < 4; ++n)
        acc[m][n] = __builtin_amdgcn_mfma_f32_16x16x32_bf16(af[m], bfr[n], acc[m][n], 0, 0, 0);
    __syncthreads();
  }
  const int crow0 = (lane >> 4) * 4;
  const int ccol = lane & 15;
#pragma unroll
  for (int n = 0; n < 4; ++n) {
    int col = n0 + wc * 64 + n * 16 + ccol;
    float bv = bias[col];
#pragma unroll
    for (int m = 0; m < 4; ++m) {
      int row = m0 + wr * 64 + m * 16 + crow0;
      float* cp = C + (size_t)row * N + col;
#pragma unroll
      for (int r = 0; r < 4; ++r) cp[(size_t)r * N] = acc[m][n][r] + bv;
    }
  }
}

// ---------------- fp32 fallback ----------------
__global__ __launch_bounds__(64) void lora_h_kernel(const float* __restrict__ x,
                                                    const float* __restrict__ A,
                                                    float* __restrict__ h,
                                                    float scale, int K, int R) {
  int m = blockIdx.x, lane = threadIdx.x;
  float acc[16];
#pragma unroll
  for (int r = 0; r < 16; ++r) acc[r] = 0.f;
  for (int d = lane; d < K; d += 64) {
    float xv = x[(size_t)m * K + d];
    for (int r = 0; r < R; ++r) acc[r] += xv * A[(size_t)r * K + d];
  }
  for (int off = 32; off; off >>= 1)
    for (int r = 0; r < R; ++r) acc[r] += __shfl_down(acc[r], off);
  if (lane == 0)
    for (int r = 0; r < R; ++r) h[(size_t)m * R + r] = acc[r] * scale;
}

__global__ __launch_bounds__(256) void fgemm_fallback(const float* __restrict__ X,
                                                      const float* __restrict__ W,
                                                      const float* __restrict__ Bm,
                                                      const float* __restrict__ bias,
                                                      const float* __restrict__ h,
                                                      float* __restrict__ C,
                                                      int M, int N, int K, int R) {
  __shared__ float sX[64][20];
  __shared__ float sW[64][20];
  int nt = N >> 6;
  int bx = blockIdx.x % nt, by = blockIdx.x / nt;
  int m0 = by << 6, n0 = bx << 6;
  int t = threadIdx.x;
  int tx = t & 15, ty = t >> 4;
  float acc[4][4] = {};
  int lrr = t >> 2, lc = (t & 3) << 2;
  for (int k0 = 0; k0 < K; k0 += 16) {
    *(float4*)&sX[lrr][lc] = *(const float4*)&X[(size_t)(m0 + lrr) * K + k0 + lc];
    *(float4*)&sW[lrr][lc] = *(const float4*)&W[(size_t)(n0 + lrr) * K + k0 + lc];
    __syncthreads();
#pragma unroll
    for (int kk = 0; kk < 16; ++kk) {
      float a[4], b[4];
#pragma unroll
      for (int i = 0; i < 4; ++i) a[i] = sX[ty * 4 + i][kk];
#pragma unroll
      for (int j = 0; j < 4; ++j) b[j] = sW[tx * 4 + j][kk];
#pragma unroll
      for (int i = 0; i < 4; ++i)
#pragma unroll
        for (int j = 0; j < 4; ++j) acc[i][j] += a[i] * b[j];
    }
    __syncthreads();
  }
#pragma unroll
  for (int i = 0; i < 4; ++i) {
    int row = m0 + ty * 4 + i;
#pragma unroll
    for (int j = 0; j < 4; ++j) {
      int col = n0 + tx * 4 + j;
      float lo = 0.f;
      for (int r = 0; r < R; ++r) lo += h[(size_t)row * R + r] * Bm[(size_t)col * R + r];
      C[(size_t)row * N + col] = acc[i][j] + bias[col] + lo;
    }
  }
}

extern "C" void kernel_launch(void* const* d_in, const int* in_sizes, int n_in,
                              void* d_out, int out_size, void* d_ws, size_t ws_size,
                              hipStream_t stream) {
  const float* x    = (const float*)d_in[0];
  const float* W    = (const float*)d_in[1];
  const float* A    = (const float*)d_in[2];
  const float* Bm   = (const float*)d_in[3];
  const float* bias = (const float*)d_in[4];
  float* out = (float*)d_out;

  const int N = in_sizes[4];
  const int R = in_sizes[3] / N;
  const int K = in_sizes[2] / R;
  const int M = in_sizes[0] / K;
  const float scale = 16.0f / (float)R;

  const size_t xbytes = (size_t)M * K * 2;
  const size_t wbytes = (size_t)N * K * 2;
  const bool ws_ok = (ws_size >= xbytes + wbytes);
  const bool fast256 = ws_ok && (M % 256 == 0) && (N % 256 == 0) && (K % 128 == 0) && (K >= 256);
  const bool fast128 = ws_ok && (M % 128 == 0) && (N % 128 == 0) && (K % 32 == 0);

  if (fast256 || fast128) {
    unsigned short* xb = (unsigned short*)d_ws;
    unsigned short* wb = (unsigned short*)((char*)d_ws + xbytes);
    int n8 = M * K / 8;
    int t8 = N * K / 8;
    int total = n8 + t8;
    prep_kernel<<<dim3((total + 255) / 256), dim3(256), 0, stream>>>(x, W, A, Bm, xb, wb,
                                                                     scale, K, R, n8, t8);
    if (fast256) {
      int grid = (M / 256) * (N / 256);
      gemm256_bt_bias<<<dim3(grid), dim3(512), 0, stream>>>(xb, wb, bias, out, M, N, K);
    } else {
      int grid = (M / 128) * (N / 128);
      gemm_bt_bias<<<dim3(grid), dim3(256), 0, stream>>>(xb, wb, bias, out, M, N, K);
    }
  } else {
    float* h = (float*)d_ws;
    lora_h_kernel<<<dim3(M), dim3(64), 0, stream>>>(x, A, h, scale, K, R);
    int grid = (M / 64) * (N / 64);
    fgemm_fallback<<<dim3(grid), dim3(256), 0, stream>>>(x, W, Bm, bias, h, out, M, N, K, R);
  }
}

// Round 19
// 328.405 us; speedup vs baseline: 1.0836x; 1.0836x over previous
//
#include <hip/hip_runtime.h>
#include <hip/hip_bf16.h>

typedef short bf16x8 __attribute__((ext_vector_type(8)));
typedef float f32x4 __attribute__((ext_vector_type(4)));
typedef unsigned short ushort8v __attribute__((ext_vector_type(8)));

#define SBAR() asm volatile("s_barrier" ::: "memory")

__device__ __forceinline__ unsigned short f2bf(float f) {
  unsigned u = __builtin_bit_cast(unsigned, f);
  u += 0x7fffu + ((u >> 16) & 1u);   // round-to-nearest-even
  return (unsigned short)(u >> 16);
}

__device__ __forceinline__ void gload_lds16(const unsigned short* g, unsigned short* l) {
  __builtin_amdgcn_global_load_lds((const __attribute__((address_space(1))) void*)g,
                                   (__attribute__((address_space(3))) void*)l, 16, 0, 0);
}

// ---------------- fused prep: xb = bf16(x); wb = bf16(W + scale*B@A) ----------------
__global__ __launch_bounds__(256) void prep_kernel(const float* __restrict__ x,
                                                   const float* __restrict__ W,
                                                   const float* __restrict__ A,
                                                   const float* __restrict__ Bm,
                                                   unsigned short* __restrict__ xb,
                                                   unsigned short* __restrict__ wb,
                                                   float scale, int K, int R, int n8, int t8) {
  int i = blockIdx.x * 256 + threadIdx.x;
  if (i < n8) {
    const float4* p = (const float4*)x + (size_t)i * 2;
    float4 a = p[0], b = p[1];
    ushort8v v;
    v[0] = f2bf(a.x); v[1] = f2bf(a.y); v[2] = f2bf(a.z); v[3] = f2bf(a.w);
    v[4] = f2bf(b.x); v[5] = f2bf(b.y); v[6] = f2bf(b.z); v[7] = f2bf(b.w);
    *((ushort8v*)xb + i) = v;
    return;
  }
  int idx = i - n8;
  if (idx >= t8) return;
  int perRow = K >> 3;
  int n = idx / perRow;
  int d0 = (idx - n * perRow) << 3;
  const float4* wp = (const float4*)(W + (size_t)n * K + d0);
  float4 w0 = wp[0], w1 = wp[1];
  float acc[8] = {w0.x, w0.y, w0.z, w0.w, w1.x, w1.y, w1.z, w1.w};
#pragma unroll 4
  for (int r = 0; r < R; ++r) {
    float c = Bm[(size_t)n * R + r] * scale;
    const float4* ap = (const float4*)(A + (size_t)r * K + d0);
    float4 a0 = ap[0], a1 = ap[1];
    acc[0] += c * a0.x; acc[1] += c * a0.y; acc[2] += c * a0.z; acc[3] += c * a0.w;
    acc[4] += c * a1.x; acc[5] += c * a1.y; acc[6] += c * a1.z; acc[7] += c * a1.w;
  }
  ushort8v v;
#pragma unroll
  for (int j = 0; j < 8; ++j) v[j] = f2bf(acc[j]);
  *((ushort8v*)wb + idx) = v;
}

// -------- 256x256 bf16 GEMM: quarter-phase schedule (session-best, r11/r17) --------
// BK=64, 8 waves (2Mx4N, wave 128x64), 2 LDS buffers (2x64KB = 128KB).
// Phase = one row-quarter of the wave tile (16 MFMA, 16x16x32 shape -- the only
// conflict-free fragment geometry given gload_lds's 8-slot swizzle domain).
// B read ONCE per K-tile (P1 = 12 ds_reads, P2-P4 = 4 each). Stage 2
// gload_lds/phase; counted vmcnt(6) at phases 4 and 8 ONLY.
// A quarter-major sites; B 64-row sites; chunk-XOR swizzle (measured 0 confl).
__global__ __launch_bounds__(512, 2) void gemm256_bt_bias(const unsigned short* __restrict__ Xb,
                                                          const unsigned short* __restrict__ Wb,
                                                          const float* __restrict__ bias,
                                                          float* __restrict__ C,
                                                          int M, int N, int K) {
  __shared__ __align__(16) char lds[131072];
  const int t = threadIdx.x;
  const int wave = t >> 6, lane = t & 63;
  const int fr = lane & 15, kc = lane >> 4;
  const int wr = wave >> 2, wc = wave & 3;

  const int NTn = N >> 8;
  const int nwg = gridDim.x;
  int bid = blockIdx.x;
  if ((nwg & 7) == 0) bid = (bid & 7) * (nwg >> 3) + (bid >> 3);  // XCD swizzle
  const int tm = bid / NTn, tn = bid % NTn;
  const int m0 = tm << 8, n0 = tn << 8;

  // ---- staging sources (pre-swizzled global chunk) ----
  const int lr = t >> 3;                                  // row-in-site 0..63
  const int gch8 = ((t & 7) ^ (lr & 7)) << 3;             // swizzled chunk, elems
  const unsigned short* pa0 = Xb + (size_t)(m0 + ((lr >> 5) << 7) + (lr & 31)) * K + gch8;
  const unsigned short* pb0 = Wb + (size_t)(n0 + lr) * K + gch8;
  const size_t K32 = (size_t)32 * K, K64v = (size_t)64 * K;
  const int sdst = t * 16;

  // ---- read base pointers (conflict-free swizzle, measured 0) ----
  const int swz = (fr & 7) << 4;
  const int cb0 = (kc << 4) ^ swz;
  const int cb1 = ((4 + kc) << 4) ^ swz;
  const char* rA00 = (char*)lds + (wr * 32 + fr) * 128 + cb0;   // buf0, ks=0
  const char* rA01 = (char*)lds + (wr * 32 + fr) * 128 + cb1;   // buf0, ks=1
  const char* rA10 = rA00 + 65536;                              // buf1
  const char* rA11 = rA01 + 65536;
  const char* rB00 = (char*)lds + 32768 + wc * 8192 + fr * 128 + cb0;
  const char* rB01 = (char*)lds + 32768 + wc * 8192 + fr * 128 + cb1;
  const char* rB10 = rB00 + 65536;
  const char* rB11 = rB01 + 65536;

  f32x4 acc[8][4];
#pragma unroll
  for (int m = 0; m < 8; ++m)
#pragma unroll
    for (int n = 0; n < 4; ++n) acc[m][n] = (f32x4){0.f, 0.f, 0.f, 0.f};

  bf16x8 aQ[4], bQ[8];

#define STGA(BUF, q, COL) gload_lds16(pa0 + (size_t)(q) * K32 + (COL), \
    (unsigned short*)((char*)lds + (BUF) * 65536 + (q) * 8192 + sdst))
#define STGB(BUF, s, COL) gload_lds16(pb0 + (size_t)(s) * K64v + (COL), \
    (unsigned short*)((char*)lds + (BUF) * 65536 + 32768 + (s) * 8192 + sdst))

#define RDB(R0, R1) do { \
    bQ[0]=*(const bf16x8*)(R0);        bQ[1]=*(const bf16x8*)(R1); \
    bQ[2]=*(const bf16x8*)((R0)+2048); bQ[3]=*(const bf16x8*)((R1)+2048); \
    bQ[4]=*(const bf16x8*)((R0)+4096); bQ[5]=*(const bf16x8*)((R1)+4096); \
    bQ[6]=*(const bf16x8*)((R0)+6144); bQ[7]=*(const bf16x8*)((R1)+6144); } while (0)
#define RDA(R0, R1, q) do { \
    aQ[0]=*(const bf16x8*)((R0)+(q)*8192);      aQ[1]=*(const bf16x8*)((R1)+(q)*8192); \
    aQ[2]=*(const bf16x8*)((R0)+(q)*8192+2048); aQ[3]=*(const bf16x8*)((R1)+(q)*8192+2048); } while (0)

#define MMQ(q) do { __builtin_amdgcn_s_setprio(1); \
    _Pragma("unroll") for (int mq = 0; mq < 2; ++mq) \
    _Pragma("unroll") for (int n = 0; n < 4; ++n) \
    _Pragma("unroll") for (int ks = 0; ks < 2; ++ks) \
      acc[(q)*2+mq][n] = __builtin_amdgcn_mfma_f32_16x16x32_bf16( \
          aQ[mq*2+ks], bQ[n*2+ks], acc[(q)*2+mq][n], 0, 0, 0); \
    __builtin_amdgcn_s_setprio(0); } while (0)

  // phase: reads -> stage -> [vmcnt] -> SBAR -> lgkm(0) -> 16 MFMA -> SBAR
#define PH(RA0, RA1, q, STGS, WAITS) do { \
    RDA(RA0, RA1, q); \
    STGS WAITS \
    SBAR(); \
    asm volatile("s_waitcnt lgkmcnt(0)" ::: "memory"); \
    __builtin_amdgcn_sched_barrier(0); \
    MMQ(q); \
    SBAR(); } while (0)
#define PH_B(RA0, RA1, RB0, RB1, STGS, WAITS) do { \
    RDB(RB0, RB1); RDA(RA0, RA1, 0); \
    STGS WAITS \
    SBAR(); \
    asm volatile("s_waitcnt lgkmcnt(0)" ::: "memory"); \
    __builtin_amdgcn_sched_barrier(0); \
    MMQ(0); \
    SBAR(); } while (0)

  // iter = 2 K-tiles (buf0 then buf1). Stage ledger (steady):
  // P1: Aq2,Aq3(c+1)  P2: Bs0,Bs1(c+2)  P3: Bs2,Bs3(c+2)  P4: Aq0,Aq1(c+2)
  // P5: Aq2,Aq3(c+2)  P6: Bs0,Bs1(c+3)  P7: Bs2,Bs3(c+3)  P8: Aq0,Aq1(c+3)
  // vmcnt(6)@P4 and @P8 certify everything older than the newest 6 loads.
#define ITER(DOSTG, VM4, VM8) do { \
    PH_B(rA00, rA01, rB00, rB01, { STGA(1, 2, col + 64); STGA(1, 3, col + 64); }, ;); \
    PH(rA00, rA01, 1, { if (DOSTG) { STGB(0, 0, col + 128); STGB(0, 1, col + 128); } }, ;); \
    PH(rA00, rA01, 2, { if (DOSTG) { STGB(0, 2, col + 128); STGB(0, 3, col + 128); } }, ;); \
    PH(rA00, rA01, 3, { if (DOSTG) { STGA(0, 0, col + 128); STGA(0, 1, col + 128); } }, \
       asm volatile("s_waitcnt vmcnt(" VM4 ")" ::: "memory");); \
    PH_B(rA10, rA11, rB10, rB11, { if (DOSTG) { STGA(0, 2, col + 128); STGA(0, 3, col + 128); } }, ;); \
    PH(rA10, rA11, 1, { if (DOSTG) { STGB(1, 0, col + 192); STGB(1, 1, col + 192); } }, ;); \
    PH(rA10, rA11, 2, { if (DOSTG) { STGB(1, 2, col + 192); STGB(1, 3, col + 192); } }, ;); \
    PH(rA10, rA11, 3, { if (DOSTG) { STGA(1, 0, col + 192); STGA(1, 1, col + 192); } }, \
       asm volatile("s_waitcnt vmcnt(" VM8 ")" ::: "memory");); \
    col += 128; } while (0)

  // prologue: tile0 full (8), B(1) (4), Aq0,Aq1(1) (2) = 14 loads;
  // vmcnt(6) certifies tile0, leaves exactly the steady-state 6 in flight.
  size_t col = 0;
  STGB(0, 0, 0); STGB(0, 1, 0); STGB(0, 2, 0); STGB(0, 3, 0);
  STGA(0, 0, 0); STGA(0, 1, 0); STGA(0, 2, 0); STGA(0, 3, 0);
  STGB(1, 0, 64); STGB(1, 1, 64); STGB(1, 2, 64); STGB(1, 3, 64);
  STGA(1, 0, 64); STGA(1, 1, 64);
  asm volatile("s_waitcnt vmcnt(6)" ::: "memory");
  SBAR();

  const int NITER = K >> 7;   // launcher guarantees K%128==0, K>=256
  for (int it = 0; it < NITER - 1; ++it) ITER(1, "6", "6");
  ITER(0, "0", "0");          // last iter: P1 still stages Aq2,Aq3(NT-1); drain

  // epilogue: D map col = lane&15, row = (lane>>4)*4 + reg
  const int crow = (lane >> 4) * 4;
  const int ccol = lane & 15;
#pragma unroll
  for (int n = 0; n < 4; ++n) {
    int ccol2 = n0 + wc * 64 + n * 16 + ccol;
    float bv = bias[ccol2];
#pragma unroll
    for (int m = 0; m < 8; ++m) {
      int row = m0 + wr * 128 + m * 16 + crow;
      float* cp = C + (size_t)row * N + ccol2;
#pragma unroll
      for (int r = 0; r < 4; ++r) cp[(size_t)r * N] = acc[m][n][r] + bv;
    }
  }
#undef STGA
#undef STGB
#undef RDB
#undef RDA
#undef MMQ
#undef PH
#undef PH_B
#undef ITER
}

// ---------------- 128x128 m97-structure fallback GEMM ----------------
__global__ __launch_bounds__(256) void gemm_bt_bias(const unsigned short* __restrict__ Xb,
                                                    const unsigned short* __restrict__ Wb,
                                                    const float* __restrict__ bias,
                                                    float* __restrict__ C,
                                                    int M, int N, int K) {
  __shared__ unsigned short sA[128 * 32];
  __shared__ unsigned short sB[128 * 32];
  const int t = threadIdx.x;
  const int wave = t >> 6, lane = t & 63;
  const int NT = N >> 7;
  const int nwg = gridDim.x;
  int bid = blockIdx.x;
  if ((nwg & 7) == 0) bid = (bid & 7) * (nwg >> 3) + (bid >> 3);
  const int tm = bid / NT, tn = bid % NT;
  const int m0 = tm << 7, n0 = tn << 7;
  const int wr = wave >> 1, wc = wave & 1;

  f32x4 acc[4][4];
#pragma unroll
  for (int m = 0; m < 4; ++m)
#pragma unroll
    for (int n = 0; n < 4; ++n) acc[m][n] = (f32x4){0.f, 0.f, 0.f, 0.f};

  const unsigned short* gA0 = Xb + (size_t)(m0 + (t >> 2)) * K + (t & 3) * 8;
  const unsigned short* gA1 = Xb + (size_t)(m0 + 64 + (t >> 2)) * K + (t & 3) * 8;
  const unsigned short* gB0 = Wb + (size_t)(n0 + (t >> 2)) * K + (t & 3) * 8;
  const unsigned short* gB1 = Wb + (size_t)(n0 + 64 + (t >> 2)) * K + (t & 3) * 8;
  unsigned short* lA0 = sA + (size_t)(wave * 64) * 8;
  unsigned short* lA1 = sA + (size_t)(256 + wave * 64) * 8;
  unsigned short* lB0 = sB + (size_t)(wave * 64) * 8;
  unsigned short* lB1 = sB + (size_t)(256 + wave * 64) * 8;

  const int rrow = lane & 15;
  const int rk = (lane >> 4) * 8;

  for (int k0 = 0; k0 < K; k0 += 32) {
    gload_lds16(gA0 + k0, lA0);
    gload_lds16(gA1 + k0, lA1);
    gload_lds16(gB0 + k0, lB0);
    gload_lds16(gB1 + k0, lB1);
    __syncthreads();
    bf16x8 af[4], bfr[4];
#pragma unroll
    for (int m = 0; m < 4; ++m)
      af[m] = *(const bf16x8*)&sA[(size_t)(wr * 64 + m * 16 + rrow) * 32 + rk];
#pragma unroll
    for (int n = 0; n < 4; ++n)
      bfr[n] = *(const bf16x8*)&sB[(size_t)(wc * 64 + n * 16 + rrow) * 32 + rk];
#pragma unroll
    for (int m = 0; m < 4; ++m)
#pragma unroll
      for (int n = 0; n < 4; ++n)
        acc[m][n] = __builtin_amdgcn_mfma_f32_16x16x32_bf16(af[m], bfr[n], acc[m][n], 0, 0, 0);
    __syncthreads();
  }
  const int crow0 = (lane >> 4) * 4;
  const int ccol = lane & 15;
#pragma unroll
  for (int n = 0; n < 4; ++n) {
    int col = n0 + wc * 64 + n * 16 + ccol;
    float bv = bias[col];
#pragma unroll
    for (int m = 0; m < 4; ++m) {
      int row = m0 + wr * 64 + m * 16 + crow0;
      float* cp = C + (size_t)row * N + col;
#pragma unroll
      for (int r = 0; r < 4; ++r) cp[(size_t)r * N] = acc[m][n][r] + bv;
    }
  }
}

// ---------------- fp32 fallback ----------------
__global__ __launch_bounds__(64) void lora_h_kernel(const float* __restrict__ x,
                                                    const float* __restrict__ A,
                                                    float* __restrict__ h,
                                                    float scale, int K, int R) {
  int m = blockIdx.x, lane = threadIdx.x;
  float acc[16];
#pragma unroll
  for (int r = 0; r < 16; ++r) acc[r] = 0.f;
  for (int d = lane; d < K; d += 64) {
    float xv = x[(size_t)m * K + d];
    for (int r = 0; r < R; ++r) acc[r] += xv * A[(size_t)r * K + d];
  }
  for (int off = 32; off; off >>= 1)
    for (int r = 0; r < R; ++r) acc[r] += __shfl_down(acc[r], off);
  if (lane == 0)
    for (int r = 0; r < R; ++r) h[(size_t)m * R + r] = acc[r] * scale;
}

__global__ __launch_bounds__(256) void fgemm_fallback(const float* __restrict__ X,
                                                      const float* __restrict__ W,
                                                      const float* __restrict__ Bm,
                                                      const float* __restrict__ bias,
                                                      const float* __restrict__ h,
                                                      float* __restrict__ C,
                                                      int M, int N, int K, int R) {
  __shared__ float sX[64][20];
  __shared__ float sW[64][20];
  int nt = N >> 6;
  int bx = blockIdx.x % nt, by = blockIdx.x / nt;
  int m0 = by << 6, n0 = bx << 6;
  int t = threadIdx.x;
  int tx = t & 15, ty = t >> 4;
  float acc[4][4] = {};
  int lrr = t >> 2, lc = (t & 3) << 2;
  for (int k0 = 0; k0 < K; k0 += 16) {
    *(float4*)&sX[lrr][lc] = *(const float4*)&X[(size_t)(m0 + lrr) * K + k0 + lc];
    *(float4*)&sW[lrr][lc] = *(const float4*)&W[(size_t)(n0 + lrr) * K + k0 + lc];
    __syncthreads();
#pragma unroll
    for (int kk = 0; kk < 16; ++kk) {
      float a[4], b[4];
#pragma unroll
      for (int i = 0; i < 4; ++i) a[i] = sX[ty * 4 + i][kk];
#pragma unroll
      for (int j = 0; j < 4; ++j) b[j] = sW[tx * 4 + j][kk];
#pragma unroll
      for (int i = 0; i < 4; ++i)
#pragma unroll
        for (int j = 0; j < 4; ++j) acc[i][j] += a[i] * b[j];
    }
    __syncthreads();
  }
#pragma unroll
  for (int i = 0; i < 4; ++i) {
    int row = m0 + ty * 4 + i;
#pragma unroll
    for (int j = 0; j < 4; ++j) {
      int col = n0 + tx * 4 + j;
      float lo = 0.f;
      for (int r = 0; r < R; ++r) lo += h[(size_t)row * R + r] * Bm[(size_t)col * R + r];
      C[(size_t)row * N + col] = acc[i][j] + bias[col] + lo;
    }
  }
}

extern "C" void kernel_launch(void* const* d_in, const int* in_sizes, int n_in,
                              void* d_out, int out_size, void* d_ws, size_t ws_size,
                              hipStream_t stream) {
  const float* x    = (const float*)d_in[0];
  const float* W    = (const float*)d_in[1];
  const float* A    = (const float*)d_in[2];
  const float* Bm   = (const float*)d_in[3];
  const float* bias = (const float*)d_in[4];
  float* out = (float*)d_out;

  const int N = in_sizes[4];
  const int R = in_sizes[3] / N;
  const int K = in_sizes[2] / R;
  const int M = in_sizes[0] / K;
  const float scale = 16.0f / (float)R;

  const size_t xbytes = (size_t)M * K * 2;
  const size_t wbytes = (size_t)N * K * 2;
  const bool ws_ok = (ws_size >= xbytes + wbytes);
  const bool fast256 = ws_ok && (M % 256 == 0) && (N % 256 == 0) && (K % 128 == 0) && (K >= 256);
  const bool fast128 = ws_ok && (M % 128 == 0) && (N % 128 == 0) && (K % 32 == 0);

  if (fast256 || fast128) {
    unsigned short* xb = (unsigned short*)d_ws;
    unsigned short* wb = (unsigned short*)((char*)d_ws + xbytes);
    int n8 = M * K / 8;
    int t8 = N * K / 8;
    int total = n8 + t8;
    prep_kernel<<<dim3((total + 255) / 256), dim3(256), 0, stream>>>(x, W, A, Bm, xb, wb,
                                                                     scale, K, R, n8, t8);
    if (fast256) {
      int grid = (M / 256) * (N / 256);
      gemm256_bt_bias<<<dim3(grid), dim3(512), 0, stream>>>(xb, wb, bias, out, M, N, K);
    } else {
      int grid = (M / 128) * (N / 128);
      gemm_bt_bias<<<dim3(grid), dim3(256), 0, stream>>>(xb, wb, bias, out, M, N, K);
    }
  } else {
    float* h = (float*)d_ws;
    lora_h_kernel<<<dim3(M), dim3(64), 0, stream>>>(x, A, h, scale, K, R);
    int grid = (M / 64) * (N / 64);
    fgemm_fallback<<<dim3(grid), dim3(256), 0, stream>>>(x, W, Bm, bias, h, out, M, N, K, R);
  }
}